// Round 5
// baseline (33.231 us; speedup 1.0000x reference)
//
#include <hip/hip_runtime.h>

// CapsulePooling2D: x (32,64,64,256) f32 -> out (32,32,32,256) f32.
// All work is local to each (batch, 2x2 spatial block). One 64-lane wave
// handles TWO adjacent blocks per "pair" (lanes 0-31 = block A, 32-63 = B),
// and each wave processes TWO pairs (software-pipelined: all 16 dwordx4
// loads issue up-front; pair-1's loads stay in flight under pair-0's
// shuffle/exp compute chain). Lane l owns channels {4l..4l+3, 128+4l..131+4l}.

static constexpr float EPS = 1e-7f;

typedef float f32x4 __attribute__((ext_vector_type(4)));  // native vec for nt-store

__device__ __forceinline__ float dot4(const float4& u, const float4& v) {
    return u.x * v.x + u.y * v.y + u.z * v.z + u.w * v.w;
}

struct Px {
    float4 x0A, x0B, x1A, x1B, x2A, x2B, x3A, x3B;
};

__device__ __forceinline__ void load_pair(const float* __restrict__ p,
                                          size_t rowStride, Px& d) {
    d.x0A = *(const float4*)(p);
    d.x0B = *(const float4*)(p + 128);
    d.x1A = *(const float4*)(p + 256);
    d.x1B = *(const float4*)(p + 256 + 128);
    d.x2A = *(const float4*)(p + rowStride);
    d.x2B = *(const float4*)(p + rowStride + 128);
    d.x3A = *(const float4*)(p + rowStride + 256);
    d.x3B = *(const float4*)(p + rowStride + 256 + 128);
}

__device__ __forceinline__ void compute_pair(const Px& d, float4& aA, float4& aB) {
    float s0 = 0.f, s1 = 0.f, s2 = 0.f, s3 = 0.f;  // per-pixel scores (half-uniform)
    #pragma unroll
    for (int step = 0; step < 3; ++step) {
        float n0 = 1.f, n1 = 1.f, n2 = 1.f, n3 = 1.f;
        if (step > 0) {
            // normalize_pool_map: within-block softmax-like weights, T=2
            const float m = fmaxf(fmaxf(s0, s1), fmaxf(s2, s3));
            const float e0 = expf((s0 - m) * 0.5f);
            const float e1 = expf((s1 - m) * 0.5f);
            const float e2 = expf((s2 - m) * 0.5f);
            const float e3 = expf((s3 - m) * 0.5f);
            const float inv = 1.f / (0.25f * (e0 + e1 + e2 + e3) + EPS);
            n0 = e0 * inv; n1 = e1 * inv; n2 = e2 * inv; n3 = e3 * inv;
        }
        // a = avg-pool of weighted feature map (this lane's 8 channels)
        aA.x = 0.25f * (n0 * d.x0A.x + n1 * d.x1A.x + n2 * d.x2A.x + n3 * d.x3A.x);
        aA.y = 0.25f * (n0 * d.x0A.y + n1 * d.x1A.y + n2 * d.x2A.y + n3 * d.x3A.y);
        aA.z = 0.25f * (n0 * d.x0A.z + n1 * d.x1A.z + n2 * d.x2A.z + n3 * d.x3A.z);
        aA.w = 0.25f * (n0 * d.x0A.w + n1 * d.x1A.w + n2 * d.x2A.w + n3 * d.x3A.w);
        aB.x = 0.25f * (n0 * d.x0B.x + n1 * d.x1B.x + n2 * d.x2B.x + n3 * d.x3B.x);
        aB.y = 0.25f * (n0 * d.x0B.y + n1 * d.x1B.y + n2 * d.x2B.y + n3 * d.x3B.y);
        aB.z = 0.25f * (n0 * d.x0B.z + n1 * d.x1B.z + n2 * d.x2B.z + n3 * d.x3B.z);
        aB.w = 0.25f * (n0 * d.x0B.w + n1 * d.x1B.w + n2 * d.x2B.w + n3 * d.x3B.w);

        if (step < 2) {   // step 3's score update is dead code in the reference
            // squash scale: 1/(1 + ||a||_c + EPS), reduce over this block's 32 lanes
            float ss = dot4(aA, aA) + dot4(aB, aB);
            #pragma unroll
            for (int off = 16; off; off >>= 1) ss += __shfl_xor(ss, off, 32);
            const float scale = 1.f / (1.f + sqrtf(ss) + EPS);

            // score update: score_p += scale * sum_c x[p][c] * a_c
            float p0 = dot4(d.x0A, aA) + dot4(d.x0B, aB);
            float p1 = dot4(d.x1A, aA) + dot4(d.x1B, aB);
            float p2 = dot4(d.x2A, aA) + dot4(d.x2B, aB);
            float p3 = dot4(d.x3A, aA) + dot4(d.x3B, aB);
            #pragma unroll
            for (int off = 16; off; off >>= 1) {
                p0 += __shfl_xor(p0, off, 32);
                p1 += __shfl_xor(p1, off, 32);
                p2 += __shfl_xor(p2, off, 32);
                p3 += __shfl_xor(p3, off, 32);
            }
            s0 += p0 * scale; s1 += p1 * scale;
            s2 += p2 * scale; s3 += p3 * scale;
        }
    }
}

__global__ __launch_bounds__(256) void capsule_pool_kernel(
    const float* __restrict__ x, float* __restrict__ out)
{
    constexpr int H = 64, W = 64, C = 256;
    constexpr int HB = H / 2, WB = W / 2;   // 32 x 32 pooled grid

    const int lane   = threadIdx.x & 63;
    const int waveId = threadIdx.x >> 6;
    const int half   = lane >> 5;   // which block of the pair
    const int l      = lane & 31;   // lane within half

    const int w = blockIdx.x * 4 + waveId;   // wave id, 0..8191; pairs w and w+8192
    const size_t rowStride = (size_t)W * C;

    const float* p0; const float* p1; float* o0; float* o1;
    {
        // pair 0: pid = w ; pair 1: pid = w + 8192 (same i/jp, batch +16)
        const int jp = w & (WB / 2 - 1);
        const int i  = (w >> 4) & (HB - 1);
        const int b  = w >> 9;
        const int j  = 2 * jp + half;
        p0 = x + ((size_t)b * H + 2 * i) * rowStride + (size_t)(2 * j) * C + 4 * l;
        o0 = out + (((size_t)b * HB + i) * WB + j) * C + 4 * l;
        p1 = p0 + (size_t)16 * H * rowStride;       // batch b+16
        o1 = o0 + (size_t)16 * HB * WB * C;
    }

    Px d0, d1;
    load_pair(p0, rowStride, d0);   // 8 loads in flight
    load_pair(p1, rowStride, d1);   // +8 more — 16 outstanding per lane

    float4 aA, aB;
    compute_pair(d0, aA, aB);       // waits only on d0's loads; d1's stay in flight
    {
        const f32x4 vA = {aA.x, aA.y, aA.z, aA.w};
        const f32x4 vB = {aB.x, aB.y, aB.z, aB.w};
        __builtin_nontemporal_store(vA, (f32x4*)o0);
        __builtin_nontemporal_store(vB, (f32x4*)(o0 + 128));
    }
    compute_pair(d1, aA, aB);
    {
        const f32x4 vA = {aA.x, aA.y, aA.z, aA.w};
        const f32x4 vB = {aB.x, aB.y, aB.z, aB.w};
        __builtin_nontemporal_store(vA, (f32x4*)o1);
        __builtin_nontemporal_store(vB, (f32x4*)(o1 + 128));
    }
}

extern "C" void kernel_launch(void* const* d_in, const int* in_sizes, int n_in,
                              void* d_out, int out_size, void* d_ws, size_t ws_size,
                              hipStream_t stream) {
    const float* x = (const float*)d_in[0];
    float* out = (float*)d_out;
    // 8192 waves, each: 2 block-pairs (pipelined); 4 waves per 256-thread workgroup
    capsule_pool_kernel<<<2048, 256, 0, stream>>>(x, out);
}

// Round 6
// 30.589 us; speedup vs baseline: 1.0864x; 1.0864x over previous
//
#include <hip/hip_runtime.h>

// CapsulePooling2D: x (32,64,64,256) f32 -> out (32,32,32,256) f32.
// All work is local to each (batch, 2x2 spatial block). One 64-lane wave
// handles TWO adjacent blocks (lanes 0-31 = block A, 32-63 = block B).
// Lane l owns channels {4l..4l+3} and {128+4l..128+4l+3}.
//
// Cross-lane phase per step is fully parallelized: the squash-norm (ss)
// butterfly and all four score dot-product (p0..p3) reductions run in the
// SAME 5 shuffle stages — p0..p3 are first packed one-per-lane (k = l&3)
// via a 2-stage parity transpose, then share 3 butterfly stages with ss.
// Serial depth: 6 shuffle latencies/step vs 11 in the naive sequential form.

static constexpr float EPS = 1e-7f;

typedef float f32x4 __attribute__((ext_vector_type(4)));  // native vec for nt-store

__device__ __forceinline__ float dot4(const float4& u, const float4& v) {
    return u.x * v.x + u.y * v.y + u.z * v.z + u.w * v.w;
}

__global__ __launch_bounds__(256) void capsule_pool_kernel(
    const float* __restrict__ x, float* __restrict__ out)
{
    constexpr int H = 64, W = 64, C = 256;
    constexpr int HB = H / 2, WB = W / 2;   // 32 x 32 pooled grid

    const int lane   = threadIdx.x & 63;
    const int waveId = threadIdx.x >> 6;
    const int half   = lane >> 5;   // which block of the pair
    const int l      = lane & 31;   // lane within half

    const int pid = blockIdx.x * 4 + waveId;       // block-pair id, 0..16383
    const int jp  = pid & (WB / 2 - 1);            // 0..15 (pair of j's)
    const int i   = (pid >> 4) & (HB - 1);
    const int b   = pid >> 9;
    const int j   = 2 * jp + half;                 // this half's pooled column

    const size_t rowStride = (size_t)W * C;
    const float* p = x + ((size_t)b * H + 2 * i) * rowStride
                       + (size_t)(2 * j) * C + 4 * l;

    // 4 pixels x 8 channels: A = ch[4l..4l+3], B = ch[128+4l..128+4l+3]
    const float4 x0A = *(const float4*)(p);
    const float4 x0B = *(const float4*)(p + 128);
    const float4 x1A = *(const float4*)(p + C);
    const float4 x1B = *(const float4*)(p + C + 128);
    const float4 x2A = *(const float4*)(p + rowStride);
    const float4 x2B = *(const float4*)(p + rowStride + 128);
    const float4 x3A = *(const float4*)(p + rowStride + C);
    const float4 x3B = *(const float4*)(p + rowStride + C + 128);

    float s0 = 0.f, s1 = 0.f, s2 = 0.f, s3 = 0.f;  // per-pixel scores (half-uniform)
    float4 aA, aB;                                  // pooled weighted avg (8 ch/lane)

    const bool b0 = l & 1, b1 = l & 2;

    #pragma unroll
    for (int step = 0; step < 3; ++step) {
        float n0 = 1.f, n1 = 1.f, n2 = 1.f, n3 = 1.f;
        if (step > 0) {
            // normalize_pool_map: within-block softmax-like weights, T=2
            const float m = fmaxf(fmaxf(s0, s1), fmaxf(s2, s3));
            const float e0 = expf((s0 - m) * 0.5f);
            const float e1 = expf((s1 - m) * 0.5f);
            const float e2 = expf((s2 - m) * 0.5f);
            const float e3 = expf((s3 - m) * 0.5f);
            const float inv = 1.f / (0.25f * (e0 + e1 + e2 + e3) + EPS);
            n0 = e0 * inv; n1 = e1 * inv; n2 = e2 * inv; n3 = e3 * inv;
        }
        // a = avg-pool of weighted feature map (this lane's 8 channels)
        aA.x = 0.25f * (n0 * x0A.x + n1 * x1A.x + n2 * x2A.x + n3 * x3A.x);
        aA.y = 0.25f * (n0 * x0A.y + n1 * x1A.y + n2 * x2A.y + n3 * x3A.y);
        aA.z = 0.25f * (n0 * x0A.z + n1 * x1A.z + n2 * x2A.z + n3 * x3A.z);
        aA.w = 0.25f * (n0 * x0A.w + n1 * x1A.w + n2 * x2A.w + n3 * x3A.w);
        aB.x = 0.25f * (n0 * x0B.x + n1 * x1B.x + n2 * x2B.x + n3 * x3B.x);
        aB.y = 0.25f * (n0 * x0B.y + n1 * x1B.y + n2 * x2B.y + n3 * x3B.y);
        aB.z = 0.25f * (n0 * x0B.z + n1 * x1B.z + n2 * x2B.z + n3 * x3B.z);
        aB.w = 0.25f * (n0 * x0B.w + n1 * x1B.w + n2 * x2B.w + n3 * x3B.w);

        if (step < 2) {   // step 3's score update is dead code in the reference
            // per-lane partials: squash norm + 4 score dot-products
            float ss = dot4(aA, aA) + dot4(aB, aB);
            float p0 = dot4(x0A, aA) + dot4(x0B, aB);
            float p1 = dot4(x1A, aA) + dot4(x1B, aB);
            float p2 = dot4(x2A, aA) + dot4(x2B, aB);
            float p3 = dot4(x3A, aA) + dot4(x3B, aB);

            // stage 1 (xor 1): pack p0/p1 and p2/p3; ss butterflies alongside
            float u  = b0 ? p1 : p0;
            float uo = b0 ? p0 : p1;
            u += __shfl_xor(uo, 1, 32);
            float v  = b0 ? p3 : p2;
            float vo = b0 ? p2 : p3;
            v += __shfl_xor(vo, 1, 32);
            ss += __shfl_xor(ss, 1, 32);
            // stage 2 (xor 2): pack u/v -> r; lane k=l&3 accumulates p_k
            float r  = b1 ? v : u;
            float ro = b1 ? u : v;
            r += __shfl_xor(ro, 2, 32);
            ss += __shfl_xor(ss, 2, 32);
            // stages 3-5: shared butterflies over remaining lane bits
            #pragma unroll
            for (int off = 4; off <= 16; off <<= 1) {
                r  += __shfl_xor(r, off, 32);
                ss += __shfl_xor(ss, off, 32);
            }
            // squash scale; r at lane (l&~3)|k holds full sum of p_k
            const float scale = 1.f / (1.f + sqrtf(ss) + EPS);
            s0 += scale * __shfl(r, 0, 32);
            s1 += scale * __shfl(r, 1, 32);
            s2 += scale * __shfl(r, 2, 32);
            s3 += scale * __shfl(r, 3, 32);
        }
    }

    // out[b][i][j][c] = a_c; nontemporal (never re-read)
    float* o = out + (((size_t)b * HB + i) * WB + j) * C + 4 * l;
    const f32x4 vA = {aA.x, aA.y, aA.z, aA.w};
    const f32x4 vB = {aB.x, aB.y, aB.z, aB.w};
    __builtin_nontemporal_store(vA, (f32x4*)o);
    __builtin_nontemporal_store(vB, (f32x4*)(o + 128));
}

extern "C" void kernel_launch(void* const* d_in, const int* in_sizes, int n_in,
                              void* d_out, int out_size, void* d_ws, size_t ws_size,
                              hipStream_t stream) {
    const float* x = (const float*)d_in[0];
    float* out = (float*)d_out;
    // 16384 block-pairs, 4 waves (one pair each) per 256-thread workgroup
    capsule_pool_kernel<<<4096, 256, 0, stream>>>(x, out);
}